// Round 3
// baseline (594.857 us; speedup 1.0000x reference)
//
#include <hip/hip_runtime.h>

// Problem constants
#define D     1024
#define H     8
#define M     2048
#define IMG   49152          // 128*128*3
#define IMG4  12288          // IMG/4
#define NC    8              // m-chunks for out partial stage (256 m each)

typedef float nfloat4 __attribute__((ext_vector_type(4)));  // native vec for nontemporal builtins

// ---------------------------------------------------------------------------
// Intermediates in module-scope device globals (12.7 MB total). The harness
// re-poisons d_ws unconditionally (~492 us/iter of 1.61 GB fills — measured
// invariant across rounds 0-2), so workspace choice is perf-neutral. Every
// buffer is fully overwritten each launch before being read (g_p zeroed
// inside qproj block 0).
__device__ __align__(16) float g_q[H * D];            // 32 KB
__device__ __align__(16) float g_p[H * D];            // 32 KB (atomic target)
__device__ __align__(16) float g_logits[H * M];       // 64 KB
__device__ __align__(16) float g_w[H * M];            // 64 KB
__device__ __align__(16) float g_part[(size_t)NC * H * IMG];  // 12.6 MB

// ---------------------------------------------------------------------------
// Kernel A: q[h,e] = sum_d Q[d]*WQ[h,e,d] + bQ[h,e]
// One wave per (h,e). 8192 waves -> 2048 blocks of 256.
// Block 0 additionally zeroes g_p (the pproj atomic target) — pproj is a
// later dispatch, so no race. NOTE: the q.bK logit term is a per-head
// constant across m; softmax is shift-invariant, so it cancels — no bkdot.
__global__ __launch_bounds__(256) void qproj_kernel(
    const float* __restrict__ Q, const float* __restrict__ WQ,
    const float* __restrict__ bQ) {
  if (blockIdx.x == 0) {
    float4* p4 = (float4*)g_p;
#pragma unroll
    for (int i = 0; i < 8; ++i)
      p4[threadIdx.x + i * 256] = make_float4(0.f, 0.f, 0.f, 0.f);
  }
  int wave = (blockIdx.x * 256 + threadIdx.x) >> 6;
  int lane = threadIdx.x & 63;
  int h = wave >> 10;
  int e = wave & 1023;
  const float4* Wrow = (const float4*)(WQ + (size_t)(h * D + e) * D);
  const float4* Q4 = (const float4*)Q;
  float acc = 0.f;
#pragma unroll
  for (int i = 0; i < 4; ++i) {
    float4 w = Wrow[lane + i * 64];
    float4 qv = Q4[lane + i * 64];
    acc += w.x * qv.x + w.y * qv.y + w.z * qv.z + w.w * qv.w;
  }
#pragma unroll
  for (int off = 32; off; off >>= 1) acc += __shfl_xor(acc, off, 64);
  if (lane == 0) g_q[h * D + e] = acc + bQ[h * D + e];
}

// ---------------------------------------------------------------------------
// Kernel B: p[h,d] += sum_{e in chunk} q[h,e] * WK[h,e,d]
// grid (64 e-chunks of 16, 8 heads) = 512 blocks; each thread owns 4 consecutive d.
// Atomics: 512K small RMWs to a 32 KB region — acceptable (measured in prior
// session; partial+reduce alternatives were not faster).
__global__ __launch_bounds__(256) void pproj_kernel(
    const float* __restrict__ WK) {
  int h = blockIdx.y;
  int e0 = blockIdx.x * 16;
  __shared__ float qc[16];
  if (threadIdx.x < 16) qc[threadIdx.x] = g_q[h * D + e0 + threadIdx.x];
  __syncthreads();
  const float4* W4 = (const float4*)(WK + (size_t)h * D * D);
  float4 acc = {0.f, 0.f, 0.f, 0.f};
#pragma unroll 4
  for (int ee = 0; ee < 16; ++ee) {
    float4 w = W4[(size_t)(e0 + ee) * (D / 4) + threadIdx.x];
    float qe = qc[ee];
    acc.x += qe * w.x;
    acc.y += qe * w.y;
    acc.z += qe * w.z;
    acc.w += qe * w.w;
  }
  float* pd = g_p + h * D + threadIdx.x * 4;
  atomicAdd(pd + 0, acc.x);
  atomicAdd(pd + 1, acc.y);
  atomicAdd(pd + 2, acc.z);
  atomicAdd(pd + 3, acc.w);
}

// ---------------------------------------------------------------------------
// Kernel C: logits[h,m] = (K[m,:] . p[h,:]) / 1024   (bkdot constant dropped —
// softmax-invariant). One wave per m (all 8 heads together). 512 blocks of 256.
__global__ __launch_bounds__(256) void logits_kernel(
    const float* __restrict__ K) {
  int wave = (blockIdx.x * 256 + threadIdx.x) >> 6;
  int lane = threadIdx.x & 63;
  int m = wave;
  const float4* K4 = (const float4*)(K + (size_t)m * D);
  float acc[H];
#pragma unroll
  for (int h = 0; h < H; ++h) acc[h] = 0.f;
#pragma unroll
  for (int i = 0; i < 4; ++i) {
    float4 kv = K4[lane + i * 64];
#pragma unroll
    for (int h = 0; h < H; ++h) {
      float4 pv = ((const float4*)(g_p + h * D))[lane + i * 64];
      acc[h] += kv.x * pv.x + kv.y * pv.y + kv.z * pv.z + kv.w * pv.w;
    }
  }
#pragma unroll
  for (int h = 0; h < H; ++h) {
    float a = acc[h];
#pragma unroll
    for (int off = 32; off; off >>= 1) a += __shfl_xor(a, off, 64);
    if (lane == 0) g_logits[h * M + m] = a * (1.0f / (float)D);
  }
}

// ---------------------------------------------------------------------------
// Kernel D: softmax over m per head. 8 blocks of 256 (8 elements/thread).
__global__ __launch_bounds__(256) void softmax_kernel() {
  int h = blockIdx.x;
  int lane = threadIdx.x & 63;
  int wid = threadIdx.x >> 6;
  __shared__ float sred[8];
  float l[8];
  float mx = -1e30f;
#pragma unroll
  for (int i = 0; i < 8; ++i) {
    l[i] = g_logits[h * M + threadIdx.x + i * 256];
    mx = fmaxf(mx, l[i]);
  }
#pragma unroll
  for (int off = 32; off; off >>= 1) mx = fmaxf(mx, __shfl_xor(mx, off, 64));
  if (lane == 0) sred[wid] = mx;
  __syncthreads();
  float bmax = fmaxf(fmaxf(sred[0], sred[1]), fmaxf(sred[2], sred[3]));
  float ev[8];
  float s = 0.f;
#pragma unroll
  for (int i = 0; i < 8; ++i) {
    ev[i] = __expf(l[i] - bmax);
    s += ev[i];
  }
#pragma unroll
  for (int off = 32; off; off >>= 1) s += __shfl_xor(s, off, 64);
  if (lane == 0) sred[4 + wid] = s;
  __syncthreads();
  float tot = sred[4] + sred[5] + sred[6] + sred[7];
  float inv = 1.0f / tot;
#pragma unroll
  for (int i = 0; i < 8; ++i)
    g_w[h * M + threadIdx.x + i * 256] = ev[i] * inv;
}

// ---------------------------------------------------------------------------
// Kernel E1: partials[mc][h][j] = sum_{m in chunk of 256} w[h,m] * V[m,j]
// grid (96 col-blocks, NC=8 m-chunks) = 768 blocks of 128 threads — exactly
// 3 blocks/CU, no tail imbalance. 6 waves/CU x 8 outstanding 1KB wave-loads
// = 48KB in flight per CU >> ~9KB needed to cover HBM latency at BW.
// NC=8 halves partials traffic vs NC=16 (25.2 -> 12.6 MB each way).
// nt on V loads only (403 MB pure streaming — keep it out of L2).
__global__ __launch_bounds__(128) void out_partial_kernel(
    const float* __restrict__ V) {
  int mc = blockIdx.y;
  int m0 = mc * 256;
  int c4 = blockIdx.x * 128 + threadIdx.x;  // float4 column index [0, 12288)
  __shared__ float wc[H][256];
  for (int i = threadIdx.x; i < H * 256; i += 128)
    wc[i >> 8][i & 255] = g_w[(i >> 8) * M + m0 + (i & 255)];
  __syncthreads();
  const nfloat4* V4 = (const nfloat4*)V;
  float4 acc[H];
#pragma unroll
  for (int h = 0; h < H; ++h) acc[h] = make_float4(0.f, 0.f, 0.f, 0.f);
  for (int mm = 0; mm < 256; mm += 8) {
    nfloat4 v[8];
#pragma unroll
    for (int j = 0; j < 8; ++j)
      v[j] = __builtin_nontemporal_load(&V4[(size_t)(m0 + mm + j) * IMG4 + c4]);
#pragma unroll
    for (int h = 0; h < H; ++h) {
#pragma unroll
      for (int j = 0; j < 8; ++j) {
        float wj = wc[h][mm + j];
        acc[h].x += wj * v[j].x;
        acc[h].y += wj * v[j].y;
        acc[h].z += wj * v[j].z;
        acc[h].w += wj * v[j].w;
      }
    }
  }
  float4* P4 = (float4*)g_part;
#pragma unroll
  for (int h = 0; h < H; ++h)
    P4[((size_t)mc * H + h) * IMG4 + c4] = acc[h];
}

// ---------------------------------------------------------------------------
// Kernel E2: out[h][j] = sum_mc partials[mc][h][j]. 384 blocks of 256.
// Partials (12.6 MB) are L3-resident — these reads mostly hit Infinity Cache.
__global__ __launch_bounds__(256) void out_reduce_kernel(float* __restrict__ out) {
  int idx = blockIdx.x * 256 + threadIdx.x;  // float4 index into H*IMG4 = 98304
  const float4* P4 = (const float4*)g_part;
  float4 s = make_float4(0.f, 0.f, 0.f, 0.f);
#pragma unroll
  for (int mc = 0; mc < NC; ++mc) {
    float4 v = P4[(size_t)mc * (H * IMG4) + idx];
    s.x += v.x; s.y += v.y; s.z += v.z; s.w += v.w;
  }
  ((float4*)out)[idx] = s;
}

// ---------------------------------------------------------------------------
extern "C" void kernel_launch(void* const* d_in, const int* in_sizes, int n_in,
                              void* d_out, int out_size, void* d_ws, size_t ws_size,
                              hipStream_t stream) {
  (void)in_sizes; (void)n_in; (void)d_ws; (void)ws_size; (void)out_size;
  const float* Q  = (const float*)d_in[0];
  const float* K  = (const float*)d_in[1];
  const float* V  = (const float*)d_in[2];
  const float* WQ = (const float*)d_in[3];
  const float* bQ = (const float*)d_in[4];
  const float* WK = (const float*)d_in[5];
  const float* bK = (const float*)d_in[6];
  (void)bK;  // q.bK is a per-head constant logit shift — softmax-invariant.
  float* out = (float*)d_out;

  qproj_kernel<<<dim3(2048), dim3(256), 0, stream>>>(Q, WQ, bQ);
  pproj_kernel<<<dim3(64, H), dim3(256), 0, stream>>>(WK);
  logits_kernel<<<dim3(512), dim3(256), 0, stream>>>(K);
  softmax_kernel<<<dim3(H), dim3(256), 0, stream>>>();
  out_partial_kernel<<<dim3(96, NC), dim3(128), 0, stream>>>(V);
  out_reduce_kernel<<<dim3(384), dim3(256), 0, stream>>>(out);
}

// Round 5
// 570.799 us; speedup vs baseline: 1.0421x; 1.0421x over previous
//
#include <hip/hip_runtime.h>

// Problem constants
#define D     1024
#define H     8
#define M     2048
#define IMG   49152          // 128*128*3
#define IMG4  12288          // IMG/4
#define NC    16             // m-chunks for out partial stage (128 m each)

typedef float nfloat4 __attribute__((ext_vector_type(4)));  // native vec for nontemporal builtins

// ---------------------------------------------------------------------------
// Intermediates in module-scope device globals. Harness re-poisons d_ws
// unconditionally (~492 us/iter of 1.61 GB fills — invariant rounds 0-3), so
// workspace choice is perf-neutral. Round-3 lesson: partials round-trip is
// L3-absorbed (NC=8 halving bought nothing, cost occupancy) — keep NC=16,
// 256-thread E1 blocks (12 waves/CU).
// g_p protocol: zero-initialized at module load (.bss); re-zeroed at the TAIL
// of out_reduce_kernel (last kernel) for the next iteration. Nothing reads p
// after logits within an iteration, so this is race-free.
__device__ __align__(16) float g_p[H * D];            // 32 KB (atomic target)
__device__ __align__(16) float g_logits[H * M];       // 64 KB
__device__ __align__(16) float g_w[H * M];            // 64 KB
__device__ __align__(16) float g_part[(size_t)NC * H * IMG];  // 25.2 MB

// ---------------------------------------------------------------------------
// Kernel F1 (fused qproj+pproj): block = (e-chunk of 16, head h).
// Phase 1: 4 waves each wave-dot 4 rows of WQ -> qc[16] in LDS (+bQ bias).
// Phase 2: p[h,d] += sum_{e in chunk} qc[e] * WK[h,e,d]  (atomicAdd, 4 d/thread).
// WQ/WK rows each read exactly once across the grid — same traffic as the
// two separate kernels, one fewer launch, no g_q round-trip.
// NOTE: the q.bK logit term is a per-head constant across m; softmax is
// shift-invariant, so it cancels — no bkdot kernel.
__global__ __launch_bounds__(256) void qkproj_kernel(
    const float* __restrict__ Q, const float* __restrict__ WQ,
    const float* __restrict__ bQ, const float* __restrict__ WK) {
  int h = blockIdx.y;
  int e0 = blockIdx.x * 16;
  int wid = threadIdx.x >> 6;   // 0..3
  int lane = threadIdx.x & 63;
  __shared__ float qc[16];
  const float4* Q4 = (const float4*)Q;
#pragma unroll
  for (int k = 0; k < 4; ++k) {
    int e = e0 + wid * 4 + k;
    const float4* Wrow = (const float4*)(WQ + (size_t)(h * D + e) * D);
    float acc = 0.f;
#pragma unroll
    for (int i = 0; i < 4; ++i) {
      float4 w = Wrow[lane + i * 64];
      float4 qv = Q4[lane + i * 64];
      acc += w.x * qv.x + w.y * qv.y + w.z * qv.z + w.w * qv.w;
    }
#pragma unroll
    for (int off = 32; off; off >>= 1) acc += __shfl_xor(acc, off, 64);
    if (lane == 0) qc[wid * 4 + k] = acc + bQ[h * D + e];
  }
  __syncthreads();
  const float4* W4 = (const float4*)(WK + (size_t)h * D * D);
  float4 acc = {0.f, 0.f, 0.f, 0.f};
#pragma unroll 4
  for (int ee = 0; ee < 16; ++ee) {
    float4 w = W4[(size_t)(e0 + ee) * (D / 4) + threadIdx.x];
    float qe = qc[ee];
    acc.x += qe * w.x;
    acc.y += qe * w.y;
    acc.z += qe * w.z;
    acc.w += qe * w.w;
  }
  float* pd = g_p + h * D + threadIdx.x * 4;
  atomicAdd(pd + 0, acc.x);
  atomicAdd(pd + 1, acc.y);
  atomicAdd(pd + 2, acc.z);
  atomicAdd(pd + 3, acc.w);
}

// ---------------------------------------------------------------------------
// Kernel C: logits[h,m] = (K[m,:] . p[h,:]) / 1024   (bkdot constant dropped —
// softmax-invariant). One wave per m (all 8 heads together). 512 blocks of 256.
__global__ __launch_bounds__(256) void logits_kernel(
    const float* __restrict__ K) {
  int wave = (blockIdx.x * 256 + threadIdx.x) >> 6;
  int lane = threadIdx.x & 63;
  int m = wave;
  const float4* K4 = (const float4*)(K + (size_t)m * D);
  float acc[H];
#pragma unroll
  for (int h = 0; h < H; ++h) acc[h] = 0.f;
#pragma unroll
  for (int i = 0; i < 4; ++i) {
    float4 kv = K4[lane + i * 64];
#pragma unroll
    for (int h = 0; h < H; ++h) {
      float4 pv = ((const float4*)(g_p + h * D))[lane + i * 64];
      acc[h] += kv.x * pv.x + kv.y * pv.y + kv.z * pv.z + kv.w * pv.w;
    }
  }
#pragma unroll
  for (int h = 0; h < H; ++h) {
    float a = acc[h];
#pragma unroll
    for (int off = 32; off; off >>= 1) a += __shfl_xor(a, off, 64);
    if (lane == 0) g_logits[h * M + m] = a * (1.0f / (float)D);
  }
}

// ---------------------------------------------------------------------------
// Kernel D: softmax over m per head. 8 blocks of 256 (8 elements/thread).
__global__ __launch_bounds__(256) void softmax_kernel() {
  int h = blockIdx.x;
  int lane = threadIdx.x & 63;
  int wid = threadIdx.x >> 6;
  __shared__ float sred[8];
  float l[8];
  float mx = -1e30f;
#pragma unroll
  for (int i = 0; i < 8; ++i) {
    l[i] = g_logits[h * M + threadIdx.x + i * 256];
    mx = fmaxf(mx, l[i]);
  }
#pragma unroll
  for (int off = 32; off; off >>= 1) mx = fmaxf(mx, __shfl_xor(mx, off, 64));
  if (lane == 0) sred[wid] = mx;
  __syncthreads();
  float bmax = fmaxf(fmaxf(sred[0], sred[1]), fmaxf(sred[2], sred[3]));
  float ev[8];
  float s = 0.f;
#pragma unroll
  for (int i = 0; i < 8; ++i) {
    ev[i] = __expf(l[i] - bmax);
    s += ev[i];
  }
#pragma unroll
  for (int off = 32; off; off >>= 1) s += __shfl_xor(s, off, 64);
  if (lane == 0) sred[4 + wid] = s;
  __syncthreads();
  float tot = sred[4] + sred[5] + sred[6] + sred[7];
  float inv = 1.0f / tot;
#pragma unroll
  for (int i = 0; i < 8; ++i)
    g_w[h * M + threadIdx.x + i * 256] = ev[i] * inv;
}

// ---------------------------------------------------------------------------
// Kernel E1: partials[mc][h][j] = sum_{m in chunk of 128} w[h,m] * V[m,j]
// grid (48 col-blocks, NC=16 m-chunks) = 768 blocks of 256 (3/CU, 12 waves/CU).
// Round-2-proven config. nt on V loads only (403 MB pure streaming).
__global__ __launch_bounds__(256) void out_partial_kernel(
    const float* __restrict__ V) {
  int mc = blockIdx.y;
  int m0 = mc * 128;
  int c4 = blockIdx.x * 256 + threadIdx.x;  // float4 column index [0, 12288)
  __shared__ float wc[H][128];
  for (int i = threadIdx.x; i < H * 128; i += 256)
    wc[i >> 7][i & 127] = g_w[(i >> 7) * M + m0 + (i & 127)];
  __syncthreads();
  const nfloat4* V4 = (const nfloat4*)V;
  float4 acc[H];
#pragma unroll
  for (int h = 0; h < H; ++h) acc[h] = make_float4(0.f, 0.f, 0.f, 0.f);
  for (int mm = 0; mm < 128; mm += 8) {
    nfloat4 v[8];
#pragma unroll
    for (int j = 0; j < 8; ++j)
      v[j] = __builtin_nontemporal_load(&V4[(size_t)(m0 + mm + j) * IMG4 + c4]);
#pragma unroll
    for (int h = 0; h < H; ++h) {
#pragma unroll
      for (int j = 0; j < 8; ++j) {
        float wj = wc[h][mm + j];
        acc[h].x += wj * v[j].x;
        acc[h].y += wj * v[j].y;
        acc[h].z += wj * v[j].z;
        acc[h].w += wj * v[j].w;
      }
    }
  }
  float4* P4 = (float4*)g_part;
#pragma unroll
  for (int h = 0; h < H; ++h)
    P4[((size_t)mc * H + h) * IMG4 + c4] = acc[h];
}

// ---------------------------------------------------------------------------
// Kernel E2: out[h][j] = sum_mc partials[mc][h][j]. 384 blocks of 256.
// Partials are L3-resident — reads hit Infinity Cache.
// Tail duty: blocks 0-7 re-zero g_p for the NEXT iteration (32 KB).
__global__ __launch_bounds__(256) void out_reduce_kernel(float* __restrict__ out) {
  int idx = blockIdx.x * 256 + threadIdx.x;  // float4 index into H*IMG4 = 98304
  const float4* P4 = (const float4*)g_part;
  float4 s = make_float4(0.f, 0.f, 0.f, 0.f);
#pragma unroll
  for (int mc = 0; mc < NC; ++mc) {
    float4 v = P4[(size_t)mc * (H * IMG4) + idx];
    s.x += v.x; s.y += v.y; s.z += v.z; s.w += v.w;
  }
  ((float4*)out)[idx] = s;
  if (blockIdx.x < 8)
    ((float4*)g_p)[blockIdx.x * 256 + threadIdx.x] =
        make_float4(0.f, 0.f, 0.f, 0.f);
}

// ---------------------------------------------------------------------------
extern "C" void kernel_launch(void* const* d_in, const int* in_sizes, int n_in,
                              void* d_out, int out_size, void* d_ws, size_t ws_size,
                              hipStream_t stream) {
  (void)in_sizes; (void)n_in; (void)d_ws; (void)ws_size; (void)out_size;
  const float* Q  = (const float*)d_in[0];
  const float* K  = (const float*)d_in[1];
  const float* V  = (const float*)d_in[2];
  const float* WQ = (const float*)d_in[3];
  const float* bQ = (const float*)d_in[4];
  const float* WK = (const float*)d_in[5];
  const float* bK = (const float*)d_in[6];
  (void)bK;  // q.bK is a per-head constant logit shift — softmax-invariant.
  float* out = (float*)d_out;

  qkproj_kernel<<<dim3(64, H), dim3(256), 0, stream>>>(Q, WQ, bQ, WK);
  logits_kernel<<<dim3(512), dim3(256), 0, stream>>>(K);
  softmax_kernel<<<dim3(H), dim3(256), 0, stream>>>();
  out_partial_kernel<<<dim3(48, NC), dim3(256), 0, stream>>>(V);
  out_reduce_kernel<<<dim3(384), dim3(256), 0, stream>>>(out);
}